// Round 20
// baseline (72.148 us; speedup 1.0000x reference)
//
#include <hip/hip_runtime.h>
#include <hip/hip_bf16.h>

#define SEQL 2048
#define DMODEL 1024
#define NH 16
#define HEADP 64
#define FINALD 1024

using bf16x8 = __attribute__((ext_vector_type(8))) short;    // 8 bf16 (MFMA A/B frag)
using f32x4  = __attribute__((ext_vector_type(4))) float;    // 16x16 MFMA C/D
using f32x16 = __attribute__((ext_vector_type(16))) float;   // 32x32 MFMA C/D
using u32x4  = __attribute__((ext_vector_type(4))) unsigned; // frag assembly

// counted vmcnt wait: loads stay in flight across barriers (T4)
#define WAITV(N) asm volatile("s_waitcnt vmcnt(" #N ")" ::: "memory")

// sigmoid scale folded into Q:  exp(-x/64) = 2^(x * QSCALE), QSCALE = -log2(e)/64
#define QSCALE (-0.02254211001389005f)

__device__ __forceinline__ f32x4 mfma16(bf16x8 a, bf16x8 b, f32x4 c) {
  return __builtin_amdgcn_mfma_f32_16x16x32_bf16(a, b, c, 0, 0, 0);
}

__device__ __forceinline__ unsigned short f2bf(float f) {
  return __builtin_bit_cast(unsigned short, __float2bfloat16(f));
}

// async global->LDS, 16B/lane; LDS dest = wave-uniform base + lane*16
__device__ __forceinline__ void gload16(const void* g, void* l) {
  __builtin_amdgcn_global_load_lds(
      (const __attribute__((address_space(1))) void*)g,
      (__attribute__((address_space(3))) void*)l, 16, 0, 0);
}

// ---- fused prep: weight transposes + x conversion (round-13) ------------
__global__ __launch_bounds__(256) void k_prep(
    const float* __restrict__ Qw, const float* __restrict__ Kw,
    const float* __restrict__ Vw, const float* __restrict__ Wf,
    const float* __restrict__ x,
    unsigned short* __restrict__ Wt, unsigned short* __restrict__ WfT,
    unsigned short* __restrict__ xb) {
  __shared__ float tile[64][65];
  int z = blockIdx.z;
  int t = threadIdx.x;
  if (z == 4) {
    long i0 = ((long)blockIdx.y * 16 + blockIdx.x) * 2048 + t;
#pragma unroll
    for (int k = 0; k < 8; ++k) {
      long i = i0 + k * 256;
      float4 v = reinterpret_cast<const float4*>(x)[i];
      ushort4 o;
      o.x = f2bf(v.x); o.y = f2bf(v.y); o.z = f2bf(v.z); o.w = f2bf(v.w);
      reinterpret_cast<ushort4*>(xb)[i] = o;
    }
    return;
  }
  const float* src; unsigned short* dst;
  int C, tr = blockIdx.x * 64, tc;
  if (z < 3) {
    const float* s3 = (z == 0) ? Qw : (z == 1) ? Kw : Vw;
    src = s3 + (long)blockIdx.y * 65536;
    dst = Wt + (long)z * 1048576 + (long)blockIdx.y * 65536;
    C = 64; tc = 0;
  } else {
    src = Wf; dst = WfT; C = 1024; tc = blockIdx.y * 64;
  }
  const int R = 1024;
  int r0 = t >> 4, c4 = (t & 15) * 4;
#pragma unroll
  for (int i = 0; i < 4; ++i) {
    int r = i * 16 + r0;
    float4 v = *reinterpret_cast<const float4*>(src + (long)(tr + r) * C + tc + c4);
    tile[r][c4 + 0] = v.x; tile[r][c4 + 1] = v.y;
    tile[r][c4 + 2] = v.z; tile[r][c4 + 3] = v.w;
  }
  __syncthreads();
  int r4 = (t & 15) * 4, cc0 = t >> 4;
#pragma unroll
  for (int i = 0; i < 4; ++i) {
    int c = i * 16 + cc0;
    ushort4 o;
    o.x = f2bf(tile[r4 + 0][c]); o.y = f2bf(tile[r4 + 1][c]);
    o.z = f2bf(tile[r4 + 2][c]); o.w = f2bf(tile[r4 + 3][c]);
    *reinterpret_cast<ushort4*>(dst + (long)(tc + c) * R + tr + r4) = o;
  }
}

// ---- unified LDS-staged GEMM, 128x64, BK=64, counted-vmcnt -------------
// EPI==0 Q-output is pre-scaled by QSCALE (sigmoid fold; Qb's only
// consumer is attn's QK^T).
template <int EPI>
__global__ __launch_bounds__(256) void k_gemm(
    const unsigned short* __restrict__ A,    // [M][K] bf16
    const unsigned short* __restrict__ Bt,   // [N][K] bf16 (B^T)
    int K,
    unsigned short* __restrict__ Qb,         // [H][S][P]
    unsigned short* __restrict__ Kb,         // [H][S][P]
    unsigned short* __restrict__ Vtb,        // [H][P][S]
    const float* __restrict__ bias,
    float* __restrict__ outf) {              // [S][FINAL]
  __shared__ char lds[49152];
  int flat = blockIdx.y * 16 + blockIdx.x;
  int cpx = (gridDim.x * gridDim.y) >> 3;
  flat = (flat & 7) * cpx + (flat >> 3);     // XCD k owns contiguous chunk
  int m0 = (flat & 15) << 7, n0 = (flat >> 4) * 64;
  int t = threadIdx.x;
  int l = t & 63, w = t >> 6;
  int r = l & 15, g = l >> 4;
  int wr = w >> 1, wc = w & 1;

  const unsigned short* Arow = A + (long)m0 * K;
  const unsigned short* Brow = Bt + (long)n0 * K;
  int rr = l >> 2;
  int c8s = (((l & 3) ^ ((l >> 3) & 3)) * 8);

  auto stage = [&](int buf, int k0) {
    char* base = lds + buf * 24576;
#pragma unroll
    for (int kk = 0; kk < 2; ++kk) {
      char* dA = base + kk * 8192 + w * 2048;
      char* dB = base + 16384 + kk * 4096 + w * 1024;
      int kc = k0 + kk * 32 + c8s;
      gload16(Arow + (long)(w * 32 + rr) * K + kc, dA);
      gload16(Arow + (long)(w * 32 + 16 + rr) * K + kc, dA + 1024);
      gload16(Brow + (long)(w * 16 + rr) * K + kc, dB);
    }
  };

  int xk = (r >> 1) & 3;
  f32x4 acc[4][2] = {};
  int cur = 0, NK = K / 64;
  stage(0, 0);
  for (int kt = 0; kt < NK; ++kt) {
    __builtin_amdgcn_s_barrier();            // A: all done reading buf cur^1
    if (kt + 1 < NK) {
      stage(cur ^ 1, (kt + 1) * 64);
      WAITV(6);
    } else {
      WAITV(0);
    }
    __builtin_amdgcn_s_barrier();            // B: everyone's cur loads landed
    __builtin_amdgcn_sched_barrier(0);
    const char* base = lds + cur * 24576;
#pragma unroll
    for (int kk = 0; kk < 2; ++kk) {
      const char* As = base + kk * 8192;
      const char* Bs = base + 16384 + kk * 4096;
      bf16x8 af[4], bb[2];
#pragma unroll
      for (int i = 0; i < 4; ++i)
        af[i] = *reinterpret_cast<const bf16x8*>(As + (wr * 64 + i * 16 + r) * 64 + ((g ^ xk) * 16));
#pragma unroll
      for (int i = 0; i < 2; ++i)
        bb[i] = *reinterpret_cast<const bf16x8*>(Bs + (wc * 32 + i * 16 + r) * 64 + ((g ^ xk) * 16));
#pragma unroll
      for (int mi = 0; mi < 4; ++mi)
#pragma unroll
        for (int ni = 0; ni < 2; ++ni)
          acc[mi][ni] = mfma16(af[mi], bb[ni], acc[mi][ni]);
    }
    cur ^= 1;
  }

  if constexpr (EPI == 0) {
    int which = n0 >> 10;
    int hb = (n0 & 1023) >> 6;
    if (which < 2) {
      float sc = (which == 0) ? QSCALE : 1.0f;   // Q pre-scaled for sigmoid
      unsigned short* dst = (which == 0 ? Qb : Kb) + (long)hb * SEQL * HEADP;
#pragma unroll
      for (int mi = 0; mi < 4; ++mi) {
        int s0 = m0 + wr * 64 + mi * 16 + g * 4;
#pragma unroll
        for (int ni = 0; ni < 2; ++ni) {
          int p = wc * 32 + ni * 16 + r;
#pragma unroll
          for (int v = 0; v < 4; ++v)
            dst[(long)(s0 + v) * HEADP + p] = f2bf(acc[mi][ni][v] * sc);
        }
      }
    } else {
      unsigned short* dst = Vtb + (long)hb * HEADP * SEQL;
#pragma unroll
      for (int mi = 0; mi < 4; ++mi) {
        int s0 = m0 + wr * 64 + mi * 16 + g * 4;
#pragma unroll
        for (int ni = 0; ni < 2; ++ni) {
          int p = wc * 32 + ni * 16 + r;
          ushort4 pk;
          pk.x = f2bf(acc[mi][ni][0]); pk.y = f2bf(acc[mi][ni][1]);
          pk.z = f2bf(acc[mi][ni][2]); pk.w = f2bf(acc[mi][ni][3]);
          *reinterpret_cast<ushort4*>(dst + (long)p * SEQL + s0) = pk;
        }
      }
    }
  } else {
#pragma unroll
    for (int ni = 0; ni < 2; ++ni) {
      int c = n0 + wc * 32 + ni * 16 + r;
      float bv = bias[c];
#pragma unroll
      for (int mi = 0; mi < 4; ++mi) {
        int s0 = m0 + wr * 64 + mi * 16 + g * 4;
#pragma unroll
        for (int v = 0; v < 4; ++v)
          outf[(long)(s0 + v) * FINALD + c] = acc[mi][ni][v] + bv;
      }
    }
  }
}

// ---- fused sigmoid attention: 8 waves, KVBLK=128, PV lagged 1 iter -----
// grid 512, block 512 = 8 waves (qg = w&1, tpar = w>>1 in 0..3).
// T15-style pipeline: PV(k-1) runs from register-saved P/V frags while
// QK(k) + sigmoid(k) execute — MFMA and VALU phases overlap instead of
// serializing. oacc accumulation order over t unchanged (exact reorder).
// __launch_bounds__(512,4) pins VGPR <=128 -> 16 waves/CU preserved.
__global__ __launch_bounds__(512, 4) void k_attn(
    const unsigned short* __restrict__ Qb,   // [H][S][P] (pre-scaled by QSCALE)
    const unsigned short* __restrict__ Kb,   // [H][S][P]
    const unsigned short* __restrict__ Vtb,  // [H][P][S]
    unsigned short* __restrict__ Ab) {       // [H][S][P] bf16
  __shared__ char lds[65536];
  int b = blockIdx.x;
  int xcd = b & 7, j = b >> 3;
  int h = (xcd << 1) | (j & 1);   // heads {2*xcd, 2*xcd+1} pinned to xcd
  int sblk = j >> 1;              // 0..31 (64 q-rows each)
  int q0b = sblk * 64;
  int tid = threadIdx.x;
  int lane = tid & 63, w = tid >> 6;         // w 0..7
  int lo5 = lane & 31, hi = lane >> 5;
  int qg = w & 1, tpar = w >> 1;             // tpar 0..3
  const unsigned short* Kh = Kb + (long)h * SEQL * HEADP;
  const unsigned short* Vh = Vtb + (long)h * HEADP * SEQL;
  const unsigned short* Qrow = Qb + ((long)h * SEQL + q0b + qg * 32 + lo5) * HEADP;

  bf16x8 qf[4];
#pragma unroll
  for (int ks = 0; ks < 4; ++ks)
    qf[ks] = *reinterpret_cast<const bf16x8*>(Qrow + ks * 16 + hi * 8);

  f32x16 zz = {};
  f32x16 oacc[2] = {zz, zz};

  auto stage = [&](int buf, int t0) {
    char* kb = lds + buf * 32768 + w * 2048;      // wave w: K rows w*16..+15
#pragma unroll
    for (int jj = 0; jj < 2; ++jj) {
      int row = w * 16 + jj * 8 + (lane >> 3);
      int c = (lane & 7) ^ (row & 7);
      gload16(Kh + (long)(t0 + row) * HEADP + c * 8, kb + jj * 1024);
    }
    char* vb = lds + buf * 32768 + 16384 + w * 2048;  // wave w: vr w*32..+31
#pragma unroll
    for (int jj = 0; jj < 2; ++jj) {
      int vr = w * 32 + jj * 16 + (lane >> 2);   // 64B units: [tp=vr>>6][p=vr&63]
      int p = vr & 63, tp = vr >> 6;
      int c = (lane & 3) ^ ((p >> 1) & 3);
      gload16(Vh + (long)p * SEQL + t0 + tp * 32 + c * 8, vb + jj * 1024);
    }
  };

  bf16x8 paPrev[2];                          // P frags of tile k-1 (ts=0,1)
  bf16x8 vfPrev[4];                          // V frags of tile k-1 [ts*2+nb]
  int cur = 0;
  stage(0, 0);
  for (int t0 = 0; t0 < SEQL; t0 += 128) {   // 16 iters
    __builtin_amdgcn_s_barrier();            // A: all done reading buf cur^1
    if (t0 + 128 < SEQL) {
      stage(cur ^ 1, t0 + 128);              // 4 more (8 outstanding)
      WAITV(4);                              // cur's loads landed
    } else {
      WAITV(0);
    }
    __builtin_amdgcn_s_barrier();            // B: everyone's cur loads landed
    __builtin_amdgcn_sched_barrier(0);

    const char* kb = lds + cur * 32768;
    const char* vb = kb + 16384;
    int krow = tpar * 32 + lo5;

    // V-frags of THIS tile -> regs (consumed by PV next iteration)
    bf16x8 vfNew[4];
#pragma unroll
    for (int ts = 0; ts < 2; ++ts)
#pragma unroll
      for (int nb = 0; nb < 2; ++nb) {
        int prow = nb * 32 + lo5;
        int c = ts * 2 + hi;
        vfNew[ts * 2 + nb] = *reinterpret_cast<const bf16x8*>(
            vb + tpar * 4096 + prow * 64 + ((c ^ ((prow >> 1) & 3)) * 16));
      }

    // QK(k) + PV(k-1): independent MFMA streams; sigmoid VALU overlaps PV
    f32x16 s = zz;
    __builtin_amdgcn_s_setprio(1);
#pragma unroll
    for (int ks = 0; ks < 4; ++ks) {
      int c = ks * 2 + hi;
      bf16x8 kf = *reinterpret_cast<const bf16x8*>(
          kb + krow * 128 + ((c ^ (krow & 7)) * 16));
      s = __builtin_amdgcn_mfma_f32_32x32x16_bf16(kf, qf[ks], s, 0, 0, 0);
    }
    if (t0 > 0) {
#pragma unroll
      for (int ts = 0; ts < 2; ++ts)
#pragma unroll
        for (int nb = 0; nb < 2; ++nb)
          oacc[nb] = __builtin_amdgcn_mfma_f32_32x32x16_bf16(
              paPrev[ts], vfPrev[ts * 2 + nb], oacc[nb], 0, 0, 0);
    }
    __builtin_amdgcn_s_setprio(0);

    // sigmoid: p = rcp(1 + exp2(s))   (scale pre-folded into Q)
    float p[16];
#pragma unroll
    for (int r = 0; r < 16; ++r) {
      float e = __builtin_amdgcn_exp2f(s[r]);
      p[r] = __builtin_amdgcn_rcpf(1.0f + e);
    }
    // pack + permlane32_swap -> P frags (round-17 verified recipe)
    unsigned d[8];
#pragma unroll
    for (int gq = 0; gq < 2; ++gq) {
      unsigned x1, x2, y1, y2;
      asm("v_cvt_pk_bf16_f32 %0, %1, %2" : "=v"(x1) : "v"(p[gq*8+0]), "v"(p[gq*8+1]));
      asm("v_cvt_pk_bf16_f32 %0, %1, %2" : "=v"(x2) : "v"(p[gq*8+2]), "v"(p[gq*8+3]));
      asm("v_cvt_pk_bf16_f32 %0, %1, %2" : "=v"(y1) : "v"(p[gq*8+4]), "v"(p[gq*8+5]));
      asm("v_cvt_pk_bf16_f32 %0, %1, %2" : "=v"(y2) : "v"(p[gq*8+6]), "v"(p[gq*8+7]));
      asm volatile("v_permlane32_swap_b32 %0, %1" : "+v"(x1), "+v"(y1));
      asm volatile("v_permlane32_swap_b32 %0, %1" : "+v"(x2), "+v"(y2));
      d[gq*4+0] = x1; d[gq*4+1] = x2; d[gq*4+2] = y1; d[gq*4+3] = y2;
    }
#pragma unroll
    for (int ts = 0; ts < 2; ++ts) {
      u32x4 pu = {d[ts*4+0], d[ts*4+1], d[ts*4+2], d[ts*4+3]};
      paPrev[ts] = __builtin_bit_cast(bf16x8, pu);
    }
#pragma unroll
    for (int i = 0; i < 4; ++i) vfPrev[i] = vfNew[i];
    cur ^= 1;
  }
  // drain: PV of the last tile
  __builtin_amdgcn_s_setprio(1);
#pragma unroll
  for (int ts = 0; ts < 2; ++ts)
#pragma unroll
    for (int nb = 0; nb < 2; ++nb)
      oacc[nb] = __builtin_amdgcn_mfma_f32_32x32x16_bf16(
          paPrev[ts], vfPrev[ts * 2 + nb], oacc[nb], 0, 0, 0);
  __builtin_amdgcn_s_setprio(0);

  // ---- 4-parity reduce via LDS (64KB, reuses K/V buffers) ----
  __syncthreads();                           // all tile reads complete
  float* pr = (float*)(lds + tpar * 16384);  // [64 q][64 p] f32 per parity
#pragma unroll
  for (int nb = 0; nb < 2; ++nb)
#pragma unroll
    for (int r = 0; r < 16; ++r) {
      int q = qg * 32 + (r & 3) + 8 * (r >> 2) + 4 * hi;
      pr[q * 64 + nb * 32 + lo5] = oacc[nb][r];
    }
  __syncthreads();
  int q = tid >> 3, pc = (tid & 7) * 8;      // 64 q x 8 p-groups = 512 threads
  unsigned short* Oh = Ab + ((long)h * SEQL + q0b + q) * HEADP + pc;
#pragma unroll
  for (int k = 0; k < 2; ++k) {
    float4 sum = *reinterpret_cast<const float4*>((const float*)lds + q * 64 + pc + k * 4);
#pragma unroll
    for (int par = 1; par < 4; ++par) {
      float4 v = *reinterpret_cast<const float4*>(
          (const float*)(lds + par * 16384) + q * 64 + pc + k * 4);
      sum.x += v.x; sum.y += v.y; sum.z += v.z; sum.w += v.w;
    }
    ushort4 o;
    o.x = f2bf(sum.x); o.y = f2bf(sum.y); o.z = f2bf(sum.z); o.w = f2bf(sum.w);
    *reinterpret_cast<ushort4*>(Oh + k * 4) = o;
  }
}

// ---- launch -------------------------------------------------------------
extern "C" void kernel_launch(void* const* d_in, const int* in_sizes, int n_in,
                              void* d_out, int out_size, void* d_ws, size_t ws_size,
                              hipStream_t stream) {
  const float* x  = (const float*)d_in[0];
  const float* Qw = (const float*)d_in[1];
  const float* Kw = (const float*)d_in[2];
  const float* Vw = (const float*)d_in[3];
  const float* Wf = (const float*)d_in[4];
  const float* bf = (const float*)d_in[5];
  float* out = (float*)d_out;

  unsigned short* ws  = (unsigned short*)d_ws;
  unsigned short* xb  = ws;                // [2048][1024]       bytes [0,4M)
  unsigned short* Wt  = ws + 2097152;      // [3][16][64][1024]  bytes [4M,10M)
  unsigned short* WfT = ws + 5242880;      // [1024][1024]       bytes [10M,12M)
  unsigned short* Qb  = ws + 6291456;      // [16][2048][64]     bytes [12M,16M)
  unsigned short* Kb  = ws + 8388608;      //                    bytes [16M,20M)
  unsigned short* Vtb = ws + 10485760;     // [16][64][2048]     bytes [20M,24M)
  unsigned short* Ab  = ws + 12582912;     // [16][2048][64]     bytes [24M,28M)

  k_prep<<<dim3(16, 16, 5), 256, 0, stream>>>(Qw, Kw, Vw, Wf, x, Wt, WfT, xb);
  k_gemm<0><<<dim3(16, 48), 256, 0, stream>>>(xb, Wt, DMODEL, Qb, Kb, Vtb, nullptr, nullptr);
  k_attn<<<512, 512, 0, stream>>>(Qb, Kb, Vtb, Ab);
  k_gemm<1><<<dim3(16, 16), 256, 0, stream>>>(Ab, WfT, DMODEL, nullptr, nullptr, nullptr, bf, out);
}

// Round 21
// 71.245 us; speedup vs baseline: 1.0127x; 1.0127x over previous
//
#include <hip/hip_runtime.h>
#include <hip/hip_bf16.h>

#define SEQL 2048
#define DMODEL 1024
#define NH 16
#define HEADP 64
#define FINALD 1024

using bf16x8 = __attribute__((ext_vector_type(8))) short;    // 8 bf16 (MFMA A/B frag)
using f32x4  = __attribute__((ext_vector_type(4))) float;    // 16x16 MFMA C/D
using f32x16 = __attribute__((ext_vector_type(16))) float;   // 32x32 MFMA C/D
using u32x4  = __attribute__((ext_vector_type(4))) unsigned; // frag assembly

// counted vmcnt wait: loads stay in flight across barriers (T4)
#define WAITV(N) asm volatile("s_waitcnt vmcnt(" #N ")" ::: "memory")

// sigmoid scale folded into Q:  exp(-x/64) = 2^(x * QSCALE), QSCALE = -log2(e)/64
#define QSCALE (-0.02254211001389005f)

__device__ __forceinline__ f32x4 mfma16(bf16x8 a, bf16x8 b, f32x4 c) {
  return __builtin_amdgcn_mfma_f32_16x16x32_bf16(a, b, c, 0, 0, 0);
}

__device__ __forceinline__ unsigned short f2bf(float f) {
  return __builtin_bit_cast(unsigned short, __float2bfloat16(f));
}

// async global->LDS, 16B/lane; LDS dest = wave-uniform base + lane*16
__device__ __forceinline__ void gload16(const void* g, void* l) {
  __builtin_amdgcn_global_load_lds(
      (const __attribute__((address_space(1))) void*)g,
      (__attribute__((address_space(3))) void*)l, 16, 0, 0);
}

// ---- prep: Q/K/V weight transposes + x conversion ----------------------
// grid (16, 16, 4): z<3 -> Qw/Kw/Vw head transpose (y=head, [1024][64]);
//                   z==3 -> x f32->bf16.  (WfT transpose moved to k_attn tail.)
__global__ __launch_bounds__(256) void k_prep(
    const float* __restrict__ Qw, const float* __restrict__ Kw,
    const float* __restrict__ Vw, const float* __restrict__ x,
    unsigned short* __restrict__ Wt, unsigned short* __restrict__ xb) {
  __shared__ float tile[64][65];
  int z = blockIdx.z;
  int t = threadIdx.x;
  if (z == 3) {                               // x conversion
    long i0 = ((long)blockIdx.y * 16 + blockIdx.x) * 2048 + t;
#pragma unroll
    for (int k = 0; k < 8; ++k) {
      long i = i0 + k * 256;
      float4 v = reinterpret_cast<const float4*>(x)[i];
      ushort4 o;
      o.x = f2bf(v.x); o.y = f2bf(v.y); o.z = f2bf(v.z); o.w = f2bf(v.w);
      reinterpret_cast<ushort4*>(xb)[i] = o;
    }
    return;
  }
  const float* s3 = (z == 0) ? Qw : (z == 1) ? Kw : Vw;
  const float* src = s3 + (long)blockIdx.y * 65536;       // head slab [1024][64]
  unsigned short* dst = Wt + (long)z * 1048576 + (long)blockIdx.y * 65536;
  const int C = 64, R = 1024;
  int tr = blockIdx.x * 64;
  int r0 = t >> 4, c4 = (t & 15) * 4;
#pragma unroll
  for (int i = 0; i < 4; ++i) {
    int r = i * 16 + r0;
    float4 v = *reinterpret_cast<const float4*>(src + (long)(tr + r) * C + c4);
    tile[r][c4 + 0] = v.x; tile[r][c4 + 1] = v.y;
    tile[r][c4 + 2] = v.z; tile[r][c4 + 3] = v.w;
  }
  __syncthreads();
  int r4 = (t & 15) * 4, cc0 = t >> 4;
#pragma unroll
  for (int i = 0; i < 4; ++i) {
    int c = i * 16 + cc0;
    ushort4 o;
    o.x = f2bf(tile[r4 + 0][c]); o.y = f2bf(tile[r4 + 1][c]);
    o.z = f2bf(tile[r4 + 2][c]); o.w = f2bf(tile[r4 + 3][c]);
    *reinterpret_cast<ushort4*>(dst + (long)c * R + tr + r4) = o;
  }
}

// ---- unified LDS-staged GEMM, 128x64, BK=64, counted-vmcnt -------------
// EPI==0 Q-output pre-scaled by QSCALE (sigmoid fold; Qb's only consumer
// is attn's QK^T).
template <int EPI>
__global__ __launch_bounds__(256) void k_gemm(
    const unsigned short* __restrict__ A,    // [M][K] bf16
    const unsigned short* __restrict__ Bt,   // [N][K] bf16 (B^T)
    int K,
    unsigned short* __restrict__ Qb,         // [H][S][P]
    unsigned short* __restrict__ Kb,         // [H][S][P]
    unsigned short* __restrict__ Vtb,        // [H][P][S]
    const float* __restrict__ bias,
    float* __restrict__ outf) {              // [S][FINAL]
  __shared__ char lds[49152];
  int flat = blockIdx.y * 16 + blockIdx.x;
  int cpx = (gridDim.x * gridDim.y) >> 3;
  flat = (flat & 7) * cpx + (flat >> 3);     // XCD k owns contiguous chunk
  int m0 = (flat & 15) << 7, n0 = (flat >> 4) * 64;
  int t = threadIdx.x;
  int l = t & 63, w = t >> 6;
  int r = l & 15, g = l >> 4;
  int wr = w >> 1, wc = w & 1;

  const unsigned short* Arow = A + (long)m0 * K;
  const unsigned short* Brow = Bt + (long)n0 * K;
  int rr = l >> 2;
  int c8s = (((l & 3) ^ ((l >> 3) & 3)) * 8);

  auto stage = [&](int buf, int k0) {
    char* base = lds + buf * 24576;
#pragma unroll
    for (int kk = 0; kk < 2; ++kk) {
      char* dA = base + kk * 8192 + w * 2048;
      char* dB = base + 16384 + kk * 4096 + w * 1024;
      int kc = k0 + kk * 32 + c8s;
      gload16(Arow + (long)(w * 32 + rr) * K + kc, dA);
      gload16(Arow + (long)(w * 32 + 16 + rr) * K + kc, dA + 1024);
      gload16(Brow + (long)(w * 16 + rr) * K + kc, dB);
    }
  };

  int xk = (r >> 1) & 3;
  f32x4 acc[4][2] = {};
  int cur = 0, NK = K / 64;
  stage(0, 0);
  for (int kt = 0; kt < NK; ++kt) {
    __builtin_amdgcn_s_barrier();            // A: all done reading buf cur^1
    if (kt + 1 < NK) {
      stage(cur ^ 1, (kt + 1) * 64);
      WAITV(6);
    } else {
      WAITV(0);
    }
    __builtin_amdgcn_s_barrier();            // B: everyone's cur loads landed
    __builtin_amdgcn_sched_barrier(0);
    const char* base = lds + cur * 24576;
#pragma unroll
    for (int kk = 0; kk < 2; ++kk) {
      const char* As = base + kk * 8192;
      const char* Bs = base + 16384 + kk * 4096;
      bf16x8 af[4], bb[2];
#pragma unroll
      for (int i = 0; i < 4; ++i)
        af[i] = *reinterpret_cast<const bf16x8*>(As + (wr * 64 + i * 16 + r) * 64 + ((g ^ xk) * 16));
#pragma unroll
      for (int i = 0; i < 2; ++i)
        bb[i] = *reinterpret_cast<const bf16x8*>(Bs + (wc * 32 + i * 16 + r) * 64 + ((g ^ xk) * 16));
#pragma unroll
      for (int mi = 0; mi < 4; ++mi)
#pragma unroll
        for (int ni = 0; ni < 2; ++ni)
          acc[mi][ni] = mfma16(af[mi], bb[ni], acc[mi][ni]);
    }
    cur ^= 1;
  }

  if constexpr (EPI == 0) {
    int which = n0 >> 10;
    int hb = (n0 & 1023) >> 6;
    if (which < 2) {
      float sc = (which == 0) ? QSCALE : 1.0f;   // Q pre-scaled for sigmoid
      unsigned short* dst = (which == 0 ? Qb : Kb) + (long)hb * SEQL * HEADP;
#pragma unroll
      for (int mi = 0; mi < 4; ++mi) {
        int s0 = m0 + wr * 64 + mi * 16 + g * 4;
#pragma unroll
        for (int ni = 0; ni < 2; ++ni) {
          int p = wc * 32 + ni * 16 + r;
#pragma unroll
          for (int v = 0; v < 4; ++v)
            dst[(long)(s0 + v) * HEADP + p] = f2bf(acc[mi][ni][v] * sc);
        }
      }
    } else {
      unsigned short* dst = Vtb + (long)hb * HEADP * SEQL;
#pragma unroll
      for (int mi = 0; mi < 4; ++mi) {
        int s0 = m0 + wr * 64 + mi * 16 + g * 4;
#pragma unroll
        for (int ni = 0; ni < 2; ++ni) {
          int p = wc * 32 + ni * 16 + r;
          ushort4 pk;
          pk.x = f2bf(acc[mi][ni][0]); pk.y = f2bf(acc[mi][ni][1]);
          pk.z = f2bf(acc[mi][ni][2]); pk.w = f2bf(acc[mi][ni][3]);
          *reinterpret_cast<ushort4*>(dst + (long)p * SEQL + s0) = pk;
        }
      }
    }
  } else {
#pragma unroll
    for (int ni = 0; ni < 2; ++ni) {
      int c = n0 + wc * 32 + ni * 16 + r;
      float bv = bias[c];
#pragma unroll
      for (int mi = 0; mi < 4; ++mi) {
        int s0 = m0 + wr * 64 + mi * 16 + g * 4;
#pragma unroll
        for (int v = 0; v < 4; ++v)
          outf[(long)(s0 + v) * FINALD + c] = acc[mi][ni][v] + bv;
      }
    }
  }
}

// ---- fused sigmoid attention (r19 structure) + WfT-transpose tail ------
// grid 768: blocks 0-511 = attention (8 waves: qg = w&1, tpar = w>>1,
// KVBLK=128, 2 blocks/CU, 16 waves/CU); blocks 512-767 = WfT transpose
// tiles (ride in attn's shadow; WfT consumed only by the later gemm1).
__global__ __launch_bounds__(512) void k_attn(
    const unsigned short* __restrict__ Qb,   // [H][S][P] (pre-scaled by QSCALE)
    const unsigned short* __restrict__ Kb,   // [H][S][P]
    const unsigned short* __restrict__ Vtb,  // [H][P][S]
    unsigned short* __restrict__ Ab,         // [H][S][P] bf16
    const float* __restrict__ Wf,            // [1024][1024] f32
    unsigned short* __restrict__ WfT) {      // [1024][1024] bf16 (W_fin^T)
  __shared__ char lds[65536];
  int b = blockIdx.x;
  int tid = threadIdx.x;

  if (b >= 512) {                            // ---- WfT transpose tile ----
    int u = b - 512;                         // 0..255
    int tr = (u & 15) * 64, tc = (u >> 4) * 64;
    float (*tile)[65] = (float(*)[65])lds;
    int t = tid;
    if (t < 256) {
      int r0 = t >> 4, c4 = (t & 15) * 4;
#pragma unroll
      for (int i = 0; i < 4; ++i) {
        int r = i * 16 + r0;
        float4 v = *reinterpret_cast<const float4*>(Wf + (long)(tr + r) * 1024 + tc + c4);
        tile[r][c4 + 0] = v.x; tile[r][c4 + 1] = v.y;
        tile[r][c4 + 2] = v.z; tile[r][c4 + 3] = v.w;
      }
    }
    __syncthreads();
    if (t < 256) {
      int r4 = (t & 15) * 4, cc0 = t >> 4;
#pragma unroll
      for (int i = 0; i < 4; ++i) {
        int c = i * 16 + cc0;
        ushort4 o;
        o.x = f2bf(tile[r4 + 0][c]); o.y = f2bf(tile[r4 + 1][c]);
        o.z = f2bf(tile[r4 + 2][c]); o.w = f2bf(tile[r4 + 3][c]);
        *reinterpret_cast<ushort4*>(WfT + (long)(tc + c) * 1024 + tr + r4) = o;
      }
    }
    return;
  }

  // ---- attention ----
  int xcd = b & 7, j = b >> 3;
  int h = (xcd << 1) | (j & 1);   // heads {2*xcd, 2*xcd+1} pinned to xcd
  int sblk = j >> 1;              // 0..31 (64 q-rows each)
  int q0b = sblk * 64;
  int lane = tid & 63, w = tid >> 6;         // w 0..7
  int lo5 = lane & 31, hi = lane >> 5;
  int qg = w & 1, tpar = w >> 1;             // tpar 0..3
  const unsigned short* Kh = Kb + (long)h * SEQL * HEADP;
  const unsigned short* Vh = Vtb + (long)h * HEADP * SEQL;
  const unsigned short* Qrow = Qb + ((long)h * SEQL + q0b + qg * 32 + lo5) * HEADP;

  bf16x8 qf[4];
#pragma unroll
  for (int ks = 0; ks < 4; ++ks)
    qf[ks] = *reinterpret_cast<const bf16x8*>(Qrow + ks * 16 + hi * 8);

  f32x16 zz = {};
  f32x16 oacc[2] = {zz, zz};

  auto stage = [&](int buf, int t0) {
    char* kb = lds + buf * 32768 + w * 2048;      // wave w: K rows w*16..+15
#pragma unroll
    for (int jj = 0; jj < 2; ++jj) {
      int row = w * 16 + jj * 8 + (lane >> 3);
      int c = (lane & 7) ^ (row & 7);
      gload16(Kh + (long)(t0 + row) * HEADP + c * 8, kb + jj * 1024);
    }
    char* vb = lds + buf * 32768 + 16384 + w * 2048;  // wave w: vr w*32..+31
#pragma unroll
    for (int jj = 0; jj < 2; ++jj) {
      int vr = w * 32 + jj * 16 + (lane >> 2);   // 64B units: [tp=vr>>6][p=vr&63]
      int p = vr & 63, tp = vr >> 6;
      int c = (lane & 3) ^ ((p >> 1) & 3);
      gload16(Vh + (long)p * SEQL + t0 + tp * 32 + c * 8, vb + jj * 1024);
    }
  };

  int cur = 0;
  stage(0, 0);
  for (int t0 = 0; t0 < SEQL; t0 += 128) {   // 16 iters
    __builtin_amdgcn_s_barrier();            // A: all done reading buf cur^1
    if (t0 + 128 < SEQL) {
      stage(cur ^ 1, t0 + 128);              // 4 more (8 outstanding)
      WAITV(4);                              // cur's loads landed
    } else {
      WAITV(0);
    }
    __builtin_amdgcn_s_barrier();            // B: everyone's cur loads landed
    __builtin_amdgcn_sched_barrier(0);

    const char* kb = lds + cur * 32768;
    const char* vb = kb + 16384;
    int krow = tpar * 32 + lo5;

    // S^T[t'][q] over d=64: 4 x mfma_32x32x16(A=K, B=Q)
    f32x16 s = zz;
    __builtin_amdgcn_s_setprio(1);
#pragma unroll
    for (int ks = 0; ks < 4; ++ks) {
      int c = ks * 2 + hi;
      bf16x8 kf = *reinterpret_cast<const bf16x8*>(
          kb + krow * 128 + ((c ^ (krow & 7)) * 16));
      s = __builtin_amdgcn_mfma_f32_32x32x16_bf16(kf, qf[ks], s, 0, 0, 0);
    }
    __builtin_amdgcn_s_setprio(0);

    // sigmoid: p = rcp(1 + exp2(s))   (scale pre-folded into Q)
    float p[16];
#pragma unroll
    for (int r = 0; r < 16; ++r) {
      float e = __builtin_amdgcn_exp2f(s[r]);
      p[r] = __builtin_amdgcn_rcpf(1.0f + e);
    }
    // pack + permlane32_swap -> PV A-frags (round-17 verified recipe)
    unsigned d[8];
#pragma unroll
    for (int gq = 0; gq < 2; ++gq) {
      unsigned x1, x2, y1, y2;
      asm("v_cvt_pk_bf16_f32 %0, %1, %2" : "=v"(x1) : "v"(p[gq*8+0]), "v"(p[gq*8+1]));
      asm("v_cvt_pk_bf16_f32 %0, %1, %2" : "=v"(x2) : "v"(p[gq*8+2]), "v"(p[gq*8+3]));
      asm("v_cvt_pk_bf16_f32 %0, %1, %2" : "=v"(y1) : "v"(p[gq*8+4]), "v"(p[gq*8+5]));
      asm("v_cvt_pk_bf16_f32 %0, %1, %2" : "=v"(y2) : "v"(p[gq*8+6]), "v"(p[gq*8+7]));
      asm volatile("v_permlane32_swap_b32 %0, %1" : "+v"(x1), "+v"(y1));
      asm volatile("v_permlane32_swap_b32 %0, %1" : "+v"(x2), "+v"(y2));
      d[gq*4+0] = x1; d[gq*4+1] = x2; d[gq*4+2] = y1; d[gq*4+3] = y2;
    }

    // PV: O[q][p] += P[q][t16] V[t16][p], 2 t_sub x 2 p-halves
    __builtin_amdgcn_s_setprio(1);
#pragma unroll
    for (int ts = 0; ts < 2; ++ts) {
      u32x4 pu = {d[ts*4+0], d[ts*4+1], d[ts*4+2], d[ts*4+3]};
      bf16x8 pa = __builtin_bit_cast(bf16x8, pu);
#pragma unroll
      for (int nb = 0; nb < 2; ++nb) {
        int prow = nb * 32 + lo5;
        int c = ts * 2 + hi;
        bf16x8 vf = *reinterpret_cast<const bf16x8*>(
            vb + tpar * 4096 + prow * 64 + ((c ^ ((prow >> 1) & 3)) * 16));
        oacc[nb] = __builtin_amdgcn_mfma_f32_32x32x16_bf16(pa, vf, oacc[nb], 0, 0, 0);
      }
    }
    __builtin_amdgcn_s_setprio(0);
    cur ^= 1;
  }

  // ---- 4-parity reduce via LDS (64KB, reuses K/V buffers) ----
  __syncthreads();                           // all tile reads complete
  float* pr = (float*)(lds + tpar * 16384);  // [64 q][64 p] f32 per parity
#pragma unroll
  for (int nb = 0; nb < 2; ++nb)
#pragma unroll
    for (int r = 0; r < 16; ++r) {
      int q = qg * 32 + (r & 3) + 8 * (r >> 2) + 4 * hi;
      pr[q * 64 + nb * 32 + lo5] = oacc[nb][r];
    }
  __syncthreads();
  int q = tid >> 3, pc = (tid & 7) * 8;      // 64 q x 8 p-groups = 512 threads
  unsigned short* Oh = Ab + ((long)h * SEQL + q0b + q) * HEADP + pc;
#pragma unroll
  for (int k = 0; k < 2; ++k) {
    float4 sum = *reinterpret_cast<const float4*>((const float*)lds + q * 64 + pc + k * 4);
#pragma unroll
    for (int par = 1; par < 4; ++par) {
      float4 v = *reinterpret_cast<const float4*>(
          (const float*)(lds + par * 16384) + q * 64 + pc + k * 4);
      sum.x += v.x; sum.y += v.y; sum.z += v.z; sum.w += v.w;
    }
    ushort4 o;
    o.x = f2bf(sum.x); o.y = f2bf(sum.y); o.z = f2bf(sum.z); o.w = f2bf(sum.w);
    *reinterpret_cast<ushort4*>(Oh + k * 4) = o;
  }
}

// ---- launch -------------------------------------------------------------
extern "C" void kernel_launch(void* const* d_in, const int* in_sizes, int n_in,
                              void* d_out, int out_size, void* d_ws, size_t ws_size,
                              hipStream_t stream) {
  const float* x  = (const float*)d_in[0];
  const float* Qw = (const float*)d_in[1];
  const float* Kw = (const float*)d_in[2];
  const float* Vw = (const float*)d_in[3];
  const float* Wf = (const float*)d_in[4];
  const float* bf = (const float*)d_in[5];
  float* out = (float*)d_out;

  unsigned short* ws  = (unsigned short*)d_ws;
  unsigned short* xb  = ws;                // [2048][1024]       bytes [0,4M)
  unsigned short* Wt  = ws + 2097152;      // [3][16][64][1024]  bytes [4M,10M)
  unsigned short* WfT = ws + 5242880;      // [1024][1024]       bytes [10M,12M)
  unsigned short* Qb  = ws + 6291456;      // [16][2048][64]     bytes [12M,16M)
  unsigned short* Kb  = ws + 8388608;      //                    bytes [16M,20M)
  unsigned short* Vtb = ws + 10485760;     // [16][64][2048]     bytes [20M,24M)
  unsigned short* Ab  = ws + 12582912;     // [16][2048][64]     bytes [24M,28M)

  k_prep<<<dim3(16, 16, 4), 256, 0, stream>>>(Qw, Kw, Vw, x, Wt, xb);
  k_gemm<0><<<dim3(16, 48), 256, 0, stream>>>(xb, Wt, DMODEL, Qb, Kb, Vtb, nullptr, nullptr);
  k_attn<<<768, 512, 0, stream>>>(Qb, Kb, Vtb, Ab, Wf, WfT);
  k_gemm<1><<<dim3(16, 16), 256, 0, stream>>>(Ab, WfT, DMODEL, nullptr, nullptr, nullptr, bf, out);
}